// Round 23
// baseline (72.298 us; speedup 1.0000x reference)
//
#include <hip/hip_runtime.h>
#include <hip/hip_bf16.h>

#define DEVI __device__ __forceinline__

typedef __attribute__((ext_vector_type(4))) float f32x4;
typedef __attribute__((ext_vector_type(8))) short bf16x8;

static constexpr int BB  = 8;     // batch
static constexpr int SEQ = 1024;  // sequence length
static constexpr int DIM = 512;   // model dim = H*DQ
static constexpr int NH  = 8;     // heads
static constexpr int HD  = 64;    // head dim
static constexpr int M   = BB * SEQ;  // 8192 flattened rows

// ---------- helpers ----------

DEVI unsigned short f2bf(float x) {
  unsigned int u = __builtin_bit_cast(unsigned int, x);
  u += 0x7fffu + ((u >> 16) & 1u);
  return (unsigned short)(u >> 16);
}

DEVI float fexp2(float x) {
#if __has_builtin(__builtin_amdgcn_exp2f)
  return __builtin_amdgcn_exp2f(x);
#else
  float r; asm("v_exp_f32 %0, %1" : "=v"(r) : "v"(x)); return r;
#endif
}

DEVI void gload_lds16(const unsigned short* g, unsigned short* l) {
  __builtin_amdgcn_global_load_lds(
      (const __attribute__((address_space(1))) void*)g,
      (__attribute__((address_space(3))) void*)l, 16, 0, 0);
}

DEVI unsigned int cvtpk(float lo, float hi) {
  unsigned int r;
  asm("v_cvt_pk_bf16_f32 %0, %1, %2" : "=v"(r) : "v"(lo), "v"(hi));
  return r;
}

// ---------- all converts in ONE launch ----------
// blocks [0, 12288): elementwise fp32->bf16 for q/k/v (4096 blocks each).
// blocks [12288, 13312): 32x32 transpose-convert tiles for the 4 weights.

__global__ __launch_bounds__(256) void cvt_all_kernel(
    const float* __restrict__ q, const float* __restrict__ k, const float* __restrict__ v,
    unsigned short* __restrict__ oq, unsigned short* __restrict__ ok, unsigned short* __restrict__ ov,
    const float* __restrict__ w0, const float* __restrict__ w1,
    const float* __restrict__ w2, const float* __restrict__ w3,
    unsigned short* __restrict__ t0, unsigned short* __restrict__ t1,
    unsigned short* __restrict__ t2, unsigned short* __restrict__ t3) {
  __shared__ float tile[32][33];
  const int bid = blockIdx.x;
  if (bid < 12288) {
    const int z = bid >> 12;
    const int bl = bid & 4095;
    const float* in = (z == 0) ? q : ((z == 1) ? k : v);
    unsigned short* out = (z == 0) ? oq : ((z == 1) ? ok : ov);
    int i = (bl * 256 + threadIdx.x) * 4;
    float4 vv = *reinterpret_cast<const float4*>(in + i);
    ushort4 o;
    o.x = f2bf(vv.x); o.y = f2bf(vv.y); o.z = f2bf(vv.z); o.w = f2bf(vv.w);
    *reinterpret_cast<ushort4*>(out + i) = o;
  } else {
    const int id = bid - 12288;
    const int z = id >> 8;
    const int t = id & 255;
    const float* in = (z == 0) ? w0 : ((z == 1) ? w1 : ((z == 2) ? w2 : w3));
    unsigned short* out = (z == 0) ? t0 : ((z == 1) ? t1 : ((z == 2) ? t2 : t3));
    int n0 = (t & 15) * 32, k0 = (t >> 4) * 32;
    int tx = threadIdx.x & 31, ty = threadIdx.x >> 5;  // 32 x 8
#pragma unroll
    for (int r = 0; r < 32; r += 8)
      tile[ty + r][tx] = in[(size_t)(k0 + ty + r) * DIM + n0 + tx];
    __syncthreads();
#pragma unroll
    for (int r = 0; r < 32; r += 8)
      out[(size_t)(n0 + ty + r) * DIM + k0 + tx] = f2bf(tile[tx][ty + r]);
  }
}

// ---------- fused projection GEMM: 3-buffer, SINGLE barrier per K-step ----------
// Step = { vmcnt(4); s_barrier; STAGE((t+2)%3); ds_read+MFMA(t%3) }.
// Safety: stage target (t+2)%3 == (t-1)%3, whose reads were consumed into
// registers before barrier t (lgkmcnt precedes the MFMAs, which precede the
// barrier). vmcnt(4) retires stage-t; stage-t+1 (4 loads) stays in flight.
// LDS 48KB -> 3 blocks/CU (no occupancy confound vs R22's 64KB).
// z==0: C=qb scaled; z==1: C=kbuf; z==2: V written TRANSPOSED to vT.

__global__ __launch_bounds__(256) void gemm_proj(const unsigned short* __restrict__ Aq,
                                                 const unsigned short* __restrict__ Ak,
                                                 const unsigned short* __restrict__ Av,
                                                 const unsigned short* __restrict__ WqT,
                                                 const unsigned short* __restrict__ WkT,
                                                 const unsigned short* __restrict__ WvT,
                                                 const float* __restrict__ bq,
                                                 const float* __restrict__ bk,
                                                 const float* __restrict__ bv,
                                                 unsigned short* __restrict__ qb,
                                                 unsigned short* __restrict__ kb,
                                                 unsigned short* __restrict__ vT,
                                                 float qscale) {
  __shared__ unsigned short smem[24576];   // lA[3][4096] + lB[3][4096] = 48KB
  unsigned short* lA = smem;
  unsigned short* lB = smem + 12288;

  const int z = blockIdx.z;
  const unsigned short* A = (z == 0) ? Aq : ((z == 1) ? Ak : Av);
  const unsigned short* Bt = (z == 0) ? WqT : ((z == 1) ? WkT : WvT);
  const float* bias = (z == 0) ? bq : ((z == 1) ? bk : bv);
  const float gs = (z == 0) ? qscale : 1.0f;

  const int tid = threadIdx.x;
  const int lane = tid & 63, wave = tid >> 6;
  const int wr = wave >> 1, wc = wave & 1;         // 2x2 wave grid
  const int row0 = blockIdx.x * 128, col0 = blockIdx.y * 128;
  const int lr = lane & 15, lg = lane >> 4;
  const int axor = (lr >> 1) & 3;                  // fragment-read chunk XOR
  const int cxr = lg ^ axor;                       // swizzled chunk slot

  f32x4 acc[4][4] = {};

  const int s0a = wave * 64;
  const int sA = s0a + lane, rA = sA >> 2;
  const int koA = ((sA & 3) ^ ((sA >> 3) & 3)) * 8;
  const int s0b = 256 + wave * 64;
  const int sB = s0b + lane, rB = sB >> 2;
  const int koB = ((sB & 3) ^ ((sB >> 3) & 3)) * 8;

#define GEMM_STAGE(buf, k0)                                                              \
  do {                                                                                   \
    gload_lds16(A + (size_t)(row0 + rA) * DIM + (k0) + koA, &lA[(buf)*4096 + s0a * 8]);  \
    gload_lds16(Bt + (size_t)(col0 + rA) * DIM + (k0) + koA, &lB[(buf)*4096 + s0a * 8]); \
    gload_lds16(A + (size_t)(row0 + rB) * DIM + (k0) + koB, &lA[(buf)*4096 + s0b * 8]);  \
    gload_lds16(Bt + (size_t)(col0 + rB) * DIM + (k0) + koB, &lB[(buf)*4096 + s0b * 8]); \
  } while (0)

#define GEMM_MFMA(cur)                                                                   \
  do {                                                                                   \
    bf16x8 af[4], bfr[4];                                                                \
    _Pragma("unroll")                                                                    \
    for (int m = 0; m < 4; ++m)                                                          \
      af[m] = *reinterpret_cast<const bf16x8*>(&lA[(cur)*4096 + (wr * 64 + m * 16 + lr) * 32 + cxr * 8]); \
    _Pragma("unroll")                                                                    \
    for (int n = 0; n < 4; ++n)                                                          \
      bfr[n] = *reinterpret_cast<const bf16x8*>(&lB[(cur)*4096 + (wc * 64 + n * 16 + lr) * 32 + cxr * 8]); \
    __builtin_amdgcn_s_setprio(1);                                                       \
    _Pragma("unroll")                                                                    \
    for (int m = 0; m < 4; ++m)                                                          \
      _Pragma("unroll")                                                                  \
      for (int n = 0; n < 4; ++n)                                                        \
        acc[m][n] = __builtin_amdgcn_mfma_f32_16x16x32_bf16(af[m], bfr[n], acc[m][n], 0, 0, 0); \
    __builtin_amdgcn_s_setprio(0);                                                       \
  } while (0)

#define GEMM_SYNC(VMC)                                                                   \
  do {                                                                                   \
    asm volatile("s_waitcnt vmcnt(" #VMC ")" ::: "memory");                              \
    __builtin_amdgcn_s_barrier();                                                        \
    asm volatile("" ::: "memory");                                                       \
  } while (0)

  constexpr int NT = DIM / 32;  // 16 K-steps
  GEMM_STAGE(0, 0);
  GEMM_STAGE(1, 32);
  for (int t = 0; t < NT - 2; ++t) {
    GEMM_SYNC(4);
    GEMM_STAGE((t + 2) % 3, (t + 2) * 32);
    GEMM_MFMA(t % 3);
  }
  GEMM_SYNC(4);
  GEMM_MFMA((NT - 2) % 3);
  GEMM_SYNC(0);
  GEMM_MFMA((NT - 1) % 3);
#undef GEMM_STAGE
#undef GEMM_MFMA
#undef GEMM_SYNC

  if (z < 2) {
    // direct scalar stores (R14 numeric path)
    unsigned short* C = (z == 0) ? qb : kb;
#pragma unroll
    for (int m = 0; m < 4; ++m) {
#pragma unroll
      for (int n = 0; n < 4; ++n) {
        int col = col0 + wc * 64 + n * 16 + lr;
        int r0 = row0 + wr * 64 + m * 16 + lg * 4;
        float bvv = bias[col];
#pragma unroll
        for (int j = 0; j < 4; ++j)
          C[(size_t)(r0 + j) * DIM + col] = f2bf((acc[m][n][j] + bvv) * gs);
      }
    }
  } else {
    // V epilogue: transpose through LDS, write vT[(b*8+h)*64+dv][s] (linear).
    unsigned short* ldsT = smem;
    __syncthreads();
#pragma unroll
    for (int m = 0; m < 4; ++m) {
#pragma unroll
      for (int n = 0; n < 4; ++n) {
        const int col = wc * 64 + n * 16 + lr;
        const int r0l = wr * 64 + m * 16 + lg * 4;
        const float bvv = bias[col0 + col];
        ushort4 pk;
        pk.x = f2bf(acc[m][n][0] + bvv);
        pk.y = f2bf(acc[m][n][1] + bvv);
        pk.z = f2bf(acc[m][n][2] + bvv);
        pk.w = f2bf(acc[m][n][3] + bvv);
        *reinterpret_cast<ushort4*>(&ldsT[col * 136 + r0l]) = pk;
      }
    }
    __syncthreads();
    const int b = row0 >> 10, s_loc0 = row0 & 1023;
#pragma unroll
    for (int it = 0; it < 8; ++it) {
      int idx = it * 256 + tid;
      int c = idx >> 4, s8 = idx & 15;
      bf16x8 v = *reinterpret_cast<const bf16x8*>(&ldsT[c * 136 + s8 * 8]);
      *reinterpret_cast<bf16x8*>(
          vT + ((size_t)(b * DIM) + col0 + c) * SEQ + s_loc0 + s8 * 8) = v;
    }
  }
}

// ---------- output projection GEMM (3-buffer single-barrier, fp32 out) ----------

__global__ __launch_bounds__(256) void gemm_out(const unsigned short* __restrict__ A,
                                                const unsigned short* __restrict__ Bt,
                                                const float* __restrict__ bias,
                                                float* __restrict__ C) {
  __shared__ unsigned short lA[3][128 * 32];
  __shared__ unsigned short lB[3][128 * 32];
  const int tid = threadIdx.x;
  const int lane = tid & 63, wave = tid >> 6;
  const int wr = wave >> 1, wc = wave & 1;
  const int row0 = blockIdx.x * 128, col0 = blockIdx.y * 128;
  const int lr = lane & 15, lg = lane >> 4;
  const int axor = (lr >> 1) & 3;
  const int cxr = lg ^ axor;

  f32x4 acc[4][4] = {};

  const int s0a = wave * 64;
  const int sA = s0a + lane, rA = sA >> 2;
  const int koA = ((sA & 3) ^ ((sA >> 3) & 3)) * 8;
  const int s0b = 256 + wave * 64;
  const int sB = s0b + lane, rB = sB >> 2;
  const int koB = ((sB & 3) ^ ((sB >> 3) & 3)) * 8;

#define GEMM_STAGE(buf, k0)                                                        \
  do {                                                                             \
    gload_lds16(A + (size_t)(row0 + rA) * DIM + (k0) + koA, &lA[buf][s0a * 8]);    \
    gload_lds16(Bt + (size_t)(col0 + rA) * DIM + (k0) + koA, &lB[buf][s0a * 8]);   \
    gload_lds16(A + (size_t)(row0 + rB) * DIM + (k0) + koB, &lA[buf][s0b * 8]);    \
    gload_lds16(Bt + (size_t)(col0 + rB) * DIM + (k0) + koB, &lB[buf][s0b * 8]);   \
  } while (0)

#define GEMM_MFMA(cur)                                                             \
  do {                                                                             \
    bf16x8 af[4], bfr[4];                                                          \
    _Pragma("unroll")                                                              \
    for (int m = 0; m < 4; ++m)                                                    \
      af[m] = *reinterpret_cast<const bf16x8*>(&lA[cur][(wr * 64 + m * 16 + lr) * 32 + cxr * 8]); \
    _Pragma("unroll")                                                              \
    for (int n = 0; n < 4; ++n)                                                    \
      bfr[n] = *reinterpret_cast<const bf16x8*>(&lB[cur][(wc * 64 + n * 16 + lr) * 32 + cxr * 8]); \
    __builtin_amdgcn_s_setprio(1);                                                 \
    _Pragma("unroll")                                                              \
    for (int m = 0; m < 4; ++m)                                                    \
      _Pragma("unroll")                                                            \
      for (int n = 0; n < 4; ++n)                                                  \
        acc[m][n] = __builtin_amdgcn_mfma_f32_16x16x32_bf16(af[m], bfr[n], acc[m][n], 0, 0, 0); \
    __builtin_amdgcn_s_setprio(0);                                                 \
  } while (0)

#define GEMM_SYNC(VMC)                                                             \
  do {                                                                             \
    asm volatile("s_waitcnt vmcnt(" #VMC ")" ::: "memory");                        \
    __builtin_amdgcn_s_barrier();                                                  \
    asm volatile("" ::: "memory");                                                 \
  } while (0)

  constexpr int NT = DIM / 32;
  GEMM_STAGE(0, 0);
  GEMM_STAGE(1, 32);
  for (int t = 0; t < NT - 2; ++t) {
    GEMM_SYNC(4);
    GEMM_STAGE((t + 2) % 3, (t + 2) * 32);
    GEMM_MFMA(t % 3);
  }
  GEMM_SYNC(4);
  GEMM_MFMA((NT - 2) % 3);
  GEMM_SYNC(0);
  GEMM_MFMA((NT - 1) % 3);
#undef GEMM_STAGE
#undef GEMM_MFMA
#undef GEMM_SYNC

#pragma unroll
  for (int m = 0; m < 4; ++m) {
#pragma unroll
    for (int n = 0; n < 4; ++n) {
      int col = col0 + wc * 64 + n * 16 + lr;
      int r0 = row0 + wr * 64 + m * 16 + lg * 4;
      float bv = bias[col];
#pragma unroll
      for (int j = 0; j < 4; ++j)
        C[(size_t)(r0 + j) * DIM + col] = acc[m][n][j] + bv;
    }
  }
}

// ---------- flash attention v6-xcd (R21 validated best) ----------
// grid (BB, NH, SEQ/128): XCD = batch -> K/V L2-resident per XCD.

__global__ __launch_bounds__(512) void attn_kernel(const unsigned short* __restrict__ qb,
                                                   const unsigned short* __restrict__ kb,
                                                   const unsigned short* __restrict__ vT,
                                                   unsigned short* __restrict__ ctx) {
  __shared__ unsigned short lK[2][64 * 64];     // [ldsrow][d], chunk-swizzled, rows permuted
  __shared__ unsigned short lV[2][64 * 64];     // [dv][key], chunk-swizzled, linear keys
  __shared__ unsigned short Pl[8][16 * 72];     // per-wave P [q][stored key], stride 72

  const int b = blockIdx.x, h = blockIdx.y;     // batch on x => XCD = batch
  const int tid = threadIdx.x, lane = tid & 63, wave = tid >> 6;
  const int lr = lane & 15, lg = lane >> 4;
  const int q0 = blockIdx.z * 128 + wave * 16;

  const int sr = tid >> 3, sc = (tid & 7) ^ (sr & 7);
  const int prK = ((sr & 15) << 2) | (sr >> 4);   // key stored at LDS K-row sr
  const unsigned short* Kbase = kb + ((size_t)b * SEQ) * DIM + (size_t)h * HD;
  const unsigned short* Vbase = vT + (size_t)(b * NH + h) * HD * SEQ;

  bf16x8 qf0, qf1;
  {
    const unsigned short* qrow = qb + ((size_t)(b * SEQ) + q0 + lr) * DIM + h * HD;
    qf0 = *reinterpret_cast<const bf16x8*>(qrow + lg * 8);
    qf1 = *reinterpret_cast<const bf16x8*>(qrow + 32 + lg * 8);
  }

  float l_r[4] = {0.f, 0.f, 0.f, 0.f};
  f32x4 o_acc[4];
#pragma unroll
  for (int n = 0; n < 4; ++n) o_acc[n] = f32x4{0.f, 0.f, 0.f, 0.f};

  unsigned short* pw = Pl[wave];

#define ATT_STAGE(buf, nk)                                                          \
  do {                                                                              \
    gload_lds16(Kbase + (size_t)((nk) + prK) * DIM + sc * 8, &lK[buf][(wave * 64) * 8]); \
    gload_lds16(Vbase + (size_t)sr * SEQ + (nk) + sc * 8, &lV[buf][(wave * 64) * 8]);   \
  } while (0)

#define ATT_COMPUTE(cur)                                                            \
  do {                                                                              \
    f32x4 st[4];                                                                    \
    __builtin_amdgcn_s_setprio(1);                                                  \
    _Pragma("unroll")                                                               \
    for (int kt = 0; kt < 4; ++kt) {                                                \
      const int row = kt * 16 + lr;                                                 \
      const char* rbase = (const char*)&lK[cur][0] + row * 128;                     \
      const int sw = (row & 7) << 4;                                                \
      bf16x8 kf0 = *reinterpret_cast<const bf16x8*>(rbase + ((lg * 16) ^ sw));      \
      bf16x8 kf1 = *reinterpret_cast<const bf16x8*>(rbase + ((64 + lg * 16) ^ sw)); \
      f32x4 a = {};                                                                 \
      a = __builtin_amdgcn_mfma_f32_16x16x32_bf16(qf0, kf0, a, 0, 0, 0);            \
      a = __builtin_amdgcn_mfma_f32_16x16x32_bf16(qf1, kf1, a, 0, 0, 0);            \
      st[kt] = a;                                                                   \
    }                                                                               \
    __builtin_amdgcn_s_setprio(0);                                                  \
    _Pragma("unroll")                                                               \
    for (int j = 0; j < 4; ++j) {                                                   \
      float p0 = fexp2(st[0][j]);                                                   \
      float p1 = fexp2(st[1][j]);                                                   \
      float p2 = fexp2(st[2][j]);                                                   \
      float p3 = fexp2(st[3][j]);                                                   \
      l_r[j] += (p0 + p1) + (p2 + p3);                                              \
      uint2 pkd;                                                                    \
      pkd.x = cvtpk(p0, p1);                                                        \
      pkd.y = cvtpk(p2, p3);                                                        \
      *reinterpret_cast<uint2*>((char*)pw + (lg * 4 + j) * 144 + lr * 8) = pkd;     \
    }                                                                               \
    _Pragma("unroll")                                                               \
    for (int c = 0; c < 2; ++c) {                                                   \
      bf16x8 pf = *reinterpret_cast<const bf16x8*>((const char*)pw + lr * 144 + c * 64 + lg * 16); \
      __builtin_amdgcn_s_setprio(1);                                                \
      _Pragma("unroll")                                                             \
      for (int n = 0; n < 4; ++n) {                                                 \
        const int row = n * 16 + lr;                                                \
        bf16x8 vf = *reinterpret_cast<const bf16x8*>(                               \
            (const char*)&lV[cur][0] + row * 128 + ((c * 64 + lg * 16) ^ ((row & 7) << 4))); \
        o_acc[n] = __builtin_amdgcn_mfma_f32_16x16x32_bf16(pf, vf, o_acc[n], 0, 0, 0); \
      }                                                                             \
      __builtin_amdgcn_s_setprio(0);                                                \
    }                                                                               \
  } while (0)

  constexpr int NTT = SEQ / 64;  // 16 tiles
  ATT_STAGE(0, 0);
  for (int t = 0; t < NTT - 1; ++t) {
    const int cur = t & 1;
    ATT_STAGE(cur ^ 1, (t + 1) * 64);
    asm volatile("s_waitcnt vmcnt(2)" ::: "memory");
    __builtin_amdgcn_s_barrier();
    ATT_COMPUTE(cur);
    asm volatile("" ::: "memory");
    __builtin_amdgcn_s_barrier();
  }
  asm volatile("s_waitcnt vmcnt(0)" ::: "memory");
  __builtin_amdgcn_s_barrier();
  ATT_COMPUTE((NTT - 1) & 1);
#undef ATT_STAGE
#undef ATT_COMPUTE

  // final l reduction + normalize, bounce through pw for coalesced stores
  float invl[4];
#pragma unroll
  for (int j = 0; j < 4; ++j) {
    float l = l_r[j];
#pragma unroll
    for (int msk = 1; msk < 16; msk <<= 1) l += __shfl_xor(l, msk);
    invl[j] = 1.f / l;
  }
#pragma unroll
  for (int n = 0; n < 4; ++n)
#pragma unroll
    for (int j = 0; j < 4; ++j)
      pw[(lg * 4 + j) * 72 + n * 16 + lr] = f2bf(o_acc[n][j] * invl[j]);

#pragma unroll
  for (int it = 0; it < 2; ++it) {
    int idx = it * 64 + lane;
    int r = idx >> 3, cc = idx & 7;
    bf16x8 v = *reinterpret_cast<const bf16x8*>((const char*)pw + r * 144 + cc * 16);
    *reinterpret_cast<bf16x8*>(ctx + ((size_t)(b * SEQ) + q0 + r) * DIM + h * HD + cc * 8) = v;
  }
}

// ---------- launch ----------

extern "C" void kernel_launch(void* const* d_in, const int* in_sizes, int n_in,
                              void* d_out, int out_size, void* d_ws, size_t ws_size,
                              hipStream_t stream) {
  const float* query = (const float*)d_in[0];
  const float* key_  = (const float*)d_in[1];
  const float* value = (const float*)d_in[2];
  const float* Wq = (const float*)d_in[3];
  const float* bq = (const float*)d_in[4];
  const float* Wk = (const float*)d_in[5];
  const float* bk = (const float*)d_in[6];
  const float* Wv = (const float*)d_in[7];
  const float* bv = (const float*)d_in[8];
  const float* Wo = (const float*)d_in[9];
  const float* bo = (const float*)d_in[10];
  float* out = (float*)d_out;

  unsigned short* ws = (unsigned short*)d_ws;
  const size_t NM = (size_t)M * DIM;    // 4194304 elems
  const size_t NW = (size_t)DIM * DIM;  // 262144 elems
  unsigned short* xq   = ws;
  unsigned short* xk   = xq + NM;
  unsigned short* xv   = xk + NM;
  unsigned short* qb   = xv + NM;
  unsigned short* kbuf = qb + NM;
  unsigned short* vTb  = kbuf + NM;
  unsigned short* ctx  = vTb + NM;
  unsigned short* Wqt  = ctx + NM;
  unsigned short* Wkt  = Wqt + NW;
  unsigned short* Wvt  = Wkt + NW;
  unsigned short* Wot  = Wvt + NW;

  // all converts in one launch
  cvt_all_kernel<<<13312, 256, 0, stream>>>(query, key_, value, xq, xk, xv,
                                            Wq, Wk, Wv, Wo, Wqt, Wkt, Wvt, Wot);

  // fused projections (3-buffer single-barrier pipeline; V transposed epilogue).
  const float qscale = 0.03125f * 1.4426950408889634f;
  gemm_proj<<<dim3(M / 128, DIM / 128, 3), 256, 0, stream>>>(
      xq, xk, xv, Wqt, Wkt, Wvt, bq, bk, bv, qb, kbuf, vTb, qscale);

  // attention (batch-major grid: XCD = batch -> K/V L2-resident per XCD)
  attn_kernel<<<dim3(BB, NH, SEQ / 128), 512, 0, stream>>>(qb, kbuf, vTb, ctx);

  // output projection (3-buffer single-barrier pipeline, fp32 out + bias)
  gemm_out<<<dim3(M / 128, DIM / 128), 256, 0, stream>>>(ctx, Wot, bo, out);
}

// Round 24
// 71.495 us; speedup vs baseline: 1.0112x; 1.0112x over previous
//
#include <hip/hip_runtime.h>
#include <hip/hip_bf16.h>

#define DEVI __device__ __forceinline__

typedef __attribute__((ext_vector_type(4))) float f32x4;
typedef __attribute__((ext_vector_type(8))) short bf16x8;

static constexpr int BB  = 8;     // batch
static constexpr int SEQ = 1024;  // sequence length
static constexpr int DIM = 512;   // model dim = H*DQ
static constexpr int NH  = 8;     // heads
static constexpr int HD  = 64;    // head dim
static constexpr int M   = BB * SEQ;  // 8192 flattened rows

// ---------- helpers ----------

DEVI unsigned short f2bf(float x) {
  unsigned int u = __builtin_bit_cast(unsigned int, x);
  u += 0x7fffu + ((u >> 16) & 1u);
  return (unsigned short)(u >> 16);
}

DEVI float fexp2(float x) {
#if __has_builtin(__builtin_amdgcn_exp2f)
  return __builtin_amdgcn_exp2f(x);
#else
  float r; asm("v_exp_f32 %0, %1" : "=v"(r) : "v"(x)); return r;
#endif
}

DEVI void gload_lds16(const unsigned short* g, unsigned short* l) {
  __builtin_amdgcn_global_load_lds(
      (const __attribute__((address_space(1))) void*)g,
      (__attribute__((address_space(3))) void*)l, 16, 0, 0);
}

DEVI unsigned int cvtpk(float lo, float hi) {
  unsigned int r;
  asm("v_cvt_pk_bf16_f32 %0, %1, %2" : "=v"(r) : "v"(lo), "v"(hi));
  return r;
}

// ---------- all converts in ONE launch ----------
// blocks [0, 12288): elementwise fp32->bf16 for q/k/v (4096 blocks each).
// blocks [12288, 13312): 32x32 transpose-convert tiles for the 4 weights.

__global__ __launch_bounds__(256) void cvt_all_kernel(
    const float* __restrict__ q, const float* __restrict__ k, const float* __restrict__ v,
    unsigned short* __restrict__ oq, unsigned short* __restrict__ ok, unsigned short* __restrict__ ov,
    const float* __restrict__ w0, const float* __restrict__ w1,
    const float* __restrict__ w2, const float* __restrict__ w3,
    unsigned short* __restrict__ t0, unsigned short* __restrict__ t1,
    unsigned short* __restrict__ t2, unsigned short* __restrict__ t3) {
  __shared__ float tile[32][33];
  const int bid = blockIdx.x;
  if (bid < 12288) {
    const int z = bid >> 12;
    const int bl = bid & 4095;
    const float* in = (z == 0) ? q : ((z == 1) ? k : v);
    unsigned short* out = (z == 0) ? oq : ((z == 1) ? ok : ov);
    int i = (bl * 256 + threadIdx.x) * 4;
    float4 vv = *reinterpret_cast<const float4*>(in + i);
    ushort4 o;
    o.x = f2bf(vv.x); o.y = f2bf(vv.y); o.z = f2bf(vv.z); o.w = f2bf(vv.w);
    *reinterpret_cast<ushort4*>(out + i) = o;
  } else {
    const int id = bid - 12288;
    const int z = id >> 8;
    const int t = id & 255;
    const float* in = (z == 0) ? w0 : ((z == 1) ? w1 : ((z == 2) ? w2 : w3));
    unsigned short* out = (z == 0) ? t0 : ((z == 1) ? t1 : ((z == 2) ? t2 : t3));
    int n0 = (t & 15) * 32, k0 = (t >> 4) * 32;
    int tx = threadIdx.x & 31, ty = threadIdx.x >> 5;  // 32 x 8
#pragma unroll
    for (int r = 0; r < 32; r += 8)
      tile[ty + r][tx] = in[(size_t)(k0 + ty + r) * DIM + n0 + tx];
    __syncthreads();
#pragma unroll
    for (int r = 0; r < 32; r += 8)
      out[(size_t)(n0 + ty + r) * DIM + k0 + tx] = f2bf(tile[tx][ty + r]);
  }
}

// ---------- fused projection GEMM: 4-buffer, SINGLE barrier per K-step ----------
// Step = { vmcnt(8); s_barrier; STAGE((t+3)&3); ds_read+MFMA(t&3) }.
// z==0: C=qb scaled; z==1: C=kbuf; z==2: V written TRANSPOSED to vT.

__global__ __launch_bounds__(256) void gemm_proj(const unsigned short* __restrict__ Aq,
                                                 const unsigned short* __restrict__ Ak,
                                                 const unsigned short* __restrict__ Av,
                                                 const unsigned short* __restrict__ WqT,
                                                 const unsigned short* __restrict__ WkT,
                                                 const unsigned short* __restrict__ WvT,
                                                 const float* __restrict__ bq,
                                                 const float* __restrict__ bk,
                                                 const float* __restrict__ bv,
                                                 unsigned short* __restrict__ qb,
                                                 unsigned short* __restrict__ kb,
                                                 unsigned short* __restrict__ vT,
                                                 float qscale) {
  __shared__ unsigned short smem[32768];   // lA[4][4096] + lB[4][4096] = 64KB
  unsigned short* lA = smem;
  unsigned short* lB = smem + 16384;

  const int z = blockIdx.z;
  const unsigned short* A = (z == 0) ? Aq : ((z == 1) ? Ak : Av);
  const unsigned short* Bt = (z == 0) ? WqT : ((z == 1) ? WkT : WvT);
  const float* bias = (z == 0) ? bq : ((z == 1) ? bk : bv);
  const float gs = (z == 0) ? qscale : 1.0f;

  const int tid = threadIdx.x;
  const int lane = tid & 63, wave = tid >> 6;
  const int wr = wave >> 1, wc = wave & 1;         // 2x2 wave grid
  const int row0 = blockIdx.x * 128, col0 = blockIdx.y * 128;
  const int lr = lane & 15, lg = lane >> 4;
  const int axor = (lr >> 1) & 3;                  // fragment-read chunk XOR
  const int cxr = lg ^ axor;                       // swizzled chunk slot

  f32x4 acc[4][4] = {};

  const int s0a = wave * 64;
  const int sA = s0a + lane, rA = sA >> 2;
  const int koA = ((sA & 3) ^ ((sA >> 3) & 3)) * 8;
  const int s0b = 256 + wave * 64;
  const int sB = s0b + lane, rB = sB >> 2;
  const int koB = ((sB & 3) ^ ((sB >> 3) & 3)) * 8;

#define GEMM_STAGE(buf, k0)                                                              \
  do {                                                                                   \
    gload_lds16(A + (size_t)(row0 + rA) * DIM + (k0) + koA, &lA[(buf)*4096 + s0a * 8]);  \
    gload_lds16(Bt + (size_t)(col0 + rA) * DIM + (k0) + koA, &lB[(buf)*4096 + s0a * 8]); \
    gload_lds16(A + (size_t)(row0 + rB) * DIM + (k0) + koB, &lA[(buf)*4096 + s0b * 8]);  \
    gload_lds16(Bt + (size_t)(col0 + rB) * DIM + (k0) + koB, &lB[(buf)*4096 + s0b * 8]); \
  } while (0)

#define GEMM_MFMA(cur)                                                                   \
  do {                                                                                   \
    bf16x8 af[4], bfr[4];                                                                \
    _Pragma("unroll")                                                                    \
    for (int m = 0; m < 4; ++m)                                                          \
      af[m] = *reinterpret_cast<const bf16x8*>(&lA[(cur)*4096 + (wr * 64 + m * 16 + lr) * 32 + cxr * 8]); \
    _Pragma("unroll")                                                                    \
    for (int n = 0; n < 4; ++n)                                                          \
      bfr[n] = *reinterpret_cast<const bf16x8*>(&lB[(cur)*4096 + (wc * 64 + n * 16 + lr) * 32 + cxr * 8]); \
    __builtin_amdgcn_s_setprio(1);                                                       \
    _Pragma("unroll")                                                                    \
    for (int m = 0; m < 4; ++m)                                                          \
      _Pragma("unroll")                                                                  \
      for (int n = 0; n < 4; ++n)                                                        \
        acc[m][n] = __builtin_amdgcn_mfma_f32_16x16x32_bf16(af[m], bfr[n], acc[m][n], 0, 0, 0); \
    __builtin_amdgcn_s_setprio(0);                                                       \
  } while (0)

#define GEMM_SYNC(VMC)                                                                   \
  do {                                                                                   \
    asm volatile("s_waitcnt vmcnt(" #VMC ")" ::: "memory");                              \
    __builtin_amdgcn_s_barrier();                                                        \
    asm volatile("" ::: "memory");                                                       \
  } while (0)

  constexpr int NT = DIM / 32;  // 16 K-steps
  GEMM_STAGE(0, 0);
  GEMM_STAGE(1, 32);
  GEMM_STAGE(2, 64);
  for (int t = 0; t < NT - 3; ++t) {
    GEMM_SYNC(8);
    GEMM_STAGE((t + 3) & 3, (t + 3) * 32);
    GEMM_MFMA(t & 3);
  }
  GEMM_SYNC(8);
  GEMM_MFMA((NT - 3) & 3);
  GEMM_SYNC(4);
  GEMM_MFMA((NT - 2) & 3);
  GEMM_SYNC(0);
  GEMM_MFMA((NT - 1) & 3);
#undef GEMM_STAGE
#undef GEMM_MFMA
#undef GEMM_SYNC

  if (z < 2) {
    // direct scalar stores (R14 numeric path)
    unsigned short* C = (z == 0) ? qb : kb;
#pragma unroll
    for (int m = 0; m < 4; ++m) {
#pragma unroll
      for (int n = 0; n < 4; ++n) {
        int col = col0 + wc * 64 + n * 16 + lr;
        int r0 = row0 + wr * 64 + m * 16 + lg * 4;
        float bvv = bias[col];
#pragma unroll
        for (int j = 0; j < 4; ++j)
          C[(size_t)(r0 + j) * DIM + col] = f2bf((acc[m][n][j] + bvv) * gs);
      }
    }
  } else {
    // V epilogue: transpose through LDS, write vT[(b*8+h)*64+dv][s] (linear).
    unsigned short* ldsT = smem;
    __syncthreads();
#pragma unroll
    for (int m = 0; m < 4; ++m) {
#pragma unroll
      for (int n = 0; n < 4; ++n) {
        const int col = wc * 64 + n * 16 + lr;
        const int r0l = wr * 64 + m * 16 + lg * 4;
        const float bvv = bias[col0 + col];
        ushort4 pk;
        pk.x = f2bf(acc[m][n][0] + bvv);
        pk.y = f2bf(acc[m][n][1] + bvv);
        pk.z = f2bf(acc[m][n][2] + bvv);
        pk.w = f2bf(acc[m][n][3] + bvv);
        *reinterpret_cast<ushort4*>(&ldsT[col * 136 + r0l]) = pk;
      }
    }
    __syncthreads();
    const int b = row0 >> 10, s_loc0 = row0 & 1023;
#pragma unroll
    for (int it = 0; it < 8; ++it) {
      int idx = it * 256 + tid;
      int c = idx >> 4, s8 = idx & 15;
      bf16x8 v = *reinterpret_cast<const bf16x8*>(&ldsT[c * 136 + s8 * 8]);
      *reinterpret_cast<bf16x8*>(
          vT + ((size_t)(b * DIM) + col0 + c) * SEQ + s_loc0 + s8 * 8) = v;
    }
  }
}

// ---------- output projection GEMM (same single-barrier 4-buffer pipeline) ----------

__global__ __launch_bounds__(256) void gemm_out(const unsigned short* __restrict__ A,
                                                const unsigned short* __restrict__ Bt,
                                                const float* __restrict__ bias,
                                                float* __restrict__ C) {
  __shared__ unsigned short lA[4][128 * 32];
  __shared__ unsigned short lB[4][128 * 32];
  const int tid = threadIdx.x;
  const int lane = tid & 63, wave = tid >> 6;
  const int wr = wave >> 1, wc = wave & 1;
  const int row0 = blockIdx.x * 128, col0 = blockIdx.y * 128;
  const int lr = lane & 15, lg = lane >> 4;
  const int axor = (lr >> 1) & 3;
  const int cxr = lg ^ axor;

  f32x4 acc[4][4] = {};

  const int s0a = wave * 64;
  const int sA = s0a + lane, rA = sA >> 2;
  const int koA = ((sA & 3) ^ ((sA >> 3) & 3)) * 8;
  const int s0b = 256 + wave * 64;
  const int sB = s0b + lane, rB = sB >> 2;
  const int koB = ((sB & 3) ^ ((sB >> 3) & 3)) * 8;

#define GEMM_STAGE(buf, k0)                                                        \
  do {                                                                             \
    gload_lds16(A + (size_t)(row0 + rA) * DIM + (k0) + koA, &lA[buf][s0a * 8]);    \
    gload_lds16(Bt + (size_t)(col0 + rA) * DIM + (k0) + koA, &lB[buf][s0a * 8]);   \
    gload_lds16(A + (size_t)(row0 + rB) * DIM + (k0) + koB, &lA[buf][s0b * 8]);    \
    gload_lds16(Bt + (size_t)(col0 + rB) * DIM + (k0) + koB, &lB[buf][s0b * 8]);   \
  } while (0)

#define GEMM_MFMA(cur)                                                             \
  do {                                                                             \
    bf16x8 af[4], bfr[4];                                                          \
    _Pragma("unroll")                                                              \
    for (int m = 0; m < 4; ++m)                                                    \
      af[m] = *reinterpret_cast<const bf16x8*>(&lA[cur][(wr * 64 + m * 16 + lr) * 32 + cxr * 8]); \
    _Pragma("unroll")                                                              \
    for (int n = 0; n < 4; ++n)                                                    \
      bfr[n] = *reinterpret_cast<const bf16x8*>(&lB[cur][(wc * 64 + n * 16 + lr) * 32 + cxr * 8]); \
    __builtin_amdgcn_s_setprio(1);                                                 \
    _Pragma("unroll")                                                              \
    for (int m = 0; m < 4; ++m)                                                    \
      _Pragma("unroll")                                                            \
      for (int n = 0; n < 4; ++n)                                                  \
        acc[m][n] = __builtin_amdgcn_mfma_f32_16x16x32_bf16(af[m], bfr[n], acc[m][n], 0, 0, 0); \
    __builtin_amdgcn_s_setprio(0);                                                 \
  } while (0)

#define GEMM_SYNC(VMC)                                                             \
  do {                                                                             \
    asm volatile("s_waitcnt vmcnt(" #VMC ")" ::: "memory");                        \
    __builtin_amdgcn_s_barrier();                                                  \
    asm volatile("" ::: "memory");                                                 \
  } while (0)

  constexpr int NT = DIM / 32;
  GEMM_STAGE(0, 0);
  GEMM_STAGE(1, 32);
  GEMM_STAGE(2, 64);
  for (int t = 0; t < NT - 3; ++t) {
    GEMM_SYNC(8);
    GEMM_STAGE((t + 3) & 3, (t + 3) * 32);
    GEMM_MFMA(t & 3);
  }
  GEMM_SYNC(8);
  GEMM_MFMA((NT - 3) & 3);
  GEMM_SYNC(4);
  GEMM_MFMA((NT - 2) & 3);
  GEMM_SYNC(0);
  GEMM_MFMA((NT - 1) & 3);
#undef GEMM_STAGE
#undef GEMM_MFMA
#undef GEMM_SYNC

#pragma unroll
  for (int m = 0; m < 4; ++m) {
#pragma unroll
    for (int n = 0; n < 4; ++n) {
      int col = col0 + wc * 64 + n * 16 + lr;
      int r0 = row0 + wr * 64 + m * 16 + lg * 4;
      float bv = bias[col];
#pragma unroll
      for (int j = 0; j < 4; ++j)
        C[(size_t)(r0 + j) * DIM + col] = acc[m][n][j] + bv;
    }
  }
}

// ---------- flash attention v6-xcd (R21 validated best) ----------
// grid (BB, NH, SEQ/128): XCD = batch -> K/V L2-resident per XCD.

__global__ __launch_bounds__(512) void attn_kernel(const unsigned short* __restrict__ qb,
                                                   const unsigned short* __restrict__ kb,
                                                   const unsigned short* __restrict__ vT,
                                                   unsigned short* __restrict__ ctx) {
  __shared__ unsigned short lK[2][64 * 64];     // [ldsrow][d], chunk-swizzled, rows permuted
  __shared__ unsigned short lV[2][64 * 64];     // [dv][key], chunk-swizzled, linear keys
  __shared__ unsigned short Pl[8][16 * 72];     // per-wave P [q][stored key], stride 72

  const int b = blockIdx.x, h = blockIdx.y;     // batch on x => XCD = batch
  const int tid = threadIdx.x, lane = tid & 63, wave = tid >> 6;
  const int lr = lane & 15, lg = lane >> 4;
  const int q0 = blockIdx.z * 128 + wave * 16;

  const int sr = tid >> 3, sc = (tid & 7) ^ (sr & 7);
  const int prK = ((sr & 15) << 2) | (sr >> 4);   // key stored at LDS K-row sr
  const unsigned short* Kbase = kb + ((size_t)b * SEQ) * DIM + (size_t)h * HD;
  const unsigned short* Vbase = vT + (size_t)(b * NH + h) * HD * SEQ;

  bf16x8 qf0, qf1;
  {
    const unsigned short* qrow = qb + ((size_t)(b * SEQ) + q0 + lr) * DIM + h * HD;
    qf0 = *reinterpret_cast<const bf16x8*>(qrow + lg * 8);
    qf1 = *reinterpret_cast<const bf16x8*>(qrow + 32 + lg * 8);
  }

  float l_r[4] = {0.f, 0.f, 0.f, 0.f};
  f32x4 o_acc[4];
#pragma unroll
  for (int n = 0; n < 4; ++n) o_acc[n] = f32x4{0.f, 0.f, 0.f, 0.f};

  unsigned short* pw = Pl[wave];

#define ATT_STAGE(buf, nk)                                                          \
  do {                                                                              \
    gload_lds16(Kbase + (size_t)((nk) + prK) * DIM + sc * 8, &lK[buf][(wave * 64) * 8]); \
    gload_lds16(Vbase + (size_t)sr * SEQ + (nk) + sc * 8, &lV[buf][(wave * 64) * 8]);   \
  } while (0)

#define ATT_COMPUTE(cur)                                                            \
  do {                                                                              \
    f32x4 st[4];                                                                    \
    __builtin_amdgcn_s_setprio(1);                                                  \
    _Pragma("unroll")                                                               \
    for (int kt = 0; kt < 4; ++kt) {                                                \
      const int row = kt * 16 + lr;                                                 \
      const char* rbase = (const char*)&lK[cur][0] + row * 128;                     \
      const int sw = (row & 7) << 4;                                                \
      bf16x8 kf0 = *reinterpret_cast<const bf16x8*>(rbase + ((lg * 16) ^ sw));      \
      bf16x8 kf1 = *reinterpret_cast<const bf16x8*>(rbase + ((64 + lg * 16) ^ sw)); \
      f32x4 a = {};                                                                 \
      a = __builtin_amdgcn_mfma_f32_16x16x32_bf16(qf0, kf0, a, 0, 0, 0);            \
      a = __builtin_amdgcn_mfma_f32_16x16x32_bf16(qf1, kf1, a, 0, 0, 0);            \
      st[kt] = a;                                                                   \
    }                                                                               \
    __builtin_amdgcn_s_setprio(0);                                                  \
    _Pragma("unroll")                                                               \
    for (int j = 0; j < 4; ++j) {                                                   \
      float p0 = fexp2(st[0][j]);                                                   \
      float p1 = fexp2(st[1][j]);                                                   \
      float p2 = fexp2(st[2][j]);                                                   \
      float p3 = fexp2(st[3][j]);                                                   \
      l_r[j] += (p0 + p1) + (p2 + p3);                                              \
      uint2 pkd;                                                                    \
      pkd.x = cvtpk(p0, p1);                                                        \
      pkd.y = cvtpk(p2, p3);                                                        \
      *reinterpret_cast<uint2*>((char*)pw + (lg * 4 + j) * 144 + lr * 8) = pkd;     \
    }                                                                               \
    _Pragma("unroll")                                                               \
    for (int c = 0; c < 2; ++c) {                                                   \
      bf16x8 pf = *reinterpret_cast<const bf16x8*>((const char*)pw + lr * 144 + c * 64 + lg * 16); \
      __builtin_amdgcn_s_setprio(1);                                                \
      _Pragma("unroll")                                                             \
      for (int n = 0; n < 4; ++n) {                                                 \
        const int row = n * 16 + lr;                                                \
        bf16x8 vf = *reinterpret_cast<const bf16x8*>(                               \
            (const char*)&lV[cur][0] + row * 128 + ((c * 64 + lg * 16) ^ ((row & 7) << 4))); \
        o_acc[n] = __builtin_amdgcn_mfma_f32_16x16x32_bf16(pf, vf, o_acc[n], 0, 0, 0); \
      }                                                                             \
      __builtin_amdgcn_s_setprio(0);                                                \
    }                                                                               \
  } while (0)

  constexpr int NTT = SEQ / 64;  // 16 tiles
  ATT_STAGE(0, 0);
  for (int t = 0; t < NTT - 1; ++t) {
    const int cur = t & 1;
    ATT_STAGE(cur ^ 1, (t + 1) * 64);
    asm volatile("s_waitcnt vmcnt(2)" ::: "memory");
    __builtin_amdgcn_s_barrier();
    ATT_COMPUTE(cur);
    asm volatile("" ::: "memory");
    __builtin_amdgcn_s_barrier();
  }
  asm volatile("s_waitcnt vmcnt(0)" ::: "memory");
  __builtin_amdgcn_s_barrier();
  ATT_COMPUTE((NTT - 1) & 1);
#undef ATT_STAGE
#undef ATT_COMPUTE

  // final l reduction + normalize, bounce through pw for coalesced stores
  float invl[4];
#pragma unroll
  for (int j = 0; j < 4; ++j) {
    float l = l_r[j];
#pragma unroll
    for (int msk = 1; msk < 16; msk <<= 1) l += __shfl_xor(l, msk);
    invl[j] = 1.f / l;
  }
#pragma unroll
  for (int n = 0; n < 4; ++n)
#pragma unroll
    for (int j = 0; j < 4; ++j)
      pw[(lg * 4 + j) * 72 + n * 16 + lr] = f2bf(o_acc[n][j] * invl[j]);

#pragma unroll
  for (int it = 0; it < 2; ++it) {
    int idx = it * 64 + lane;
    int r = idx >> 3, cc = idx & 7;
    bf16x8 v = *reinterpret_cast<const bf16x8*>((const char*)pw + r * 144 + cc * 16);
    *reinterpret_cast<bf16x8*>(ctx + ((size_t)(b * SEQ) + q0 + r) * DIM + h * HD + cc * 8) = v;
  }
}

// ---------- launch ----------

extern "C" void kernel_launch(void* const* d_in, const int* in_sizes, int n_in,
                              void* d_out, int out_size, void* d_ws, size_t ws_size,
                              hipStream_t stream) {
  const float* query = (const float*)d_in[0];
  const float* key_  = (const float*)d_in[1];
  const float* value = (const float*)d_in[2];
  const float* Wq = (const float*)d_in[3];
  const float* bq = (const float*)d_in[4];
  const float* Wk = (const float*)d_in[5];
  const float* bk = (const float*)d_in[6];
  const float* Wv = (const float*)d_in[7];
  const float* bv = (const float*)d_in[8];
  const float* Wo = (const float*)d_in[9];
  const float* bo = (const float*)d_in[10];
  float* out = (float*)d_out;

  unsigned short* ws = (unsigned short*)d_ws;
  const size_t NM = (size_t)M * DIM;    // 4194304 elems
  const size_t NW = (size_t)DIM * DIM;  // 262144 elems
  unsigned short* xq   = ws;
  unsigned short* xk   = xq + NM;
  unsigned short* xv   = xk + NM;
  unsigned short* qb   = xv + NM;
  unsigned short* kbuf = qb + NM;
  unsigned short* vTb  = kbuf + NM;
  unsigned short* ctx  = vTb + NM;
  unsigned short* Wqt  = ctx + NM;
  unsigned short* Wkt  = Wqt + NW;
  unsigned short* Wvt  = Wkt + NW;
  unsigned short* Wot  = Wvt + NW;

  // all converts in one launch
  cvt_all_kernel<<<13312, 256, 0, stream>>>(query, key_, value, xq, xk, xv,
                                            Wq, Wk, Wv, Wo, Wqt, Wkt, Wvt, Wot);

  // fused projections (single-barrier 4-buffer pipeline; V transposed epilogue).
  const float qscale = 0.03125f * 1.4426950408889634f;
  gemm_proj<<<dim3(M / 128, DIM / 128, 3), 256, 0, stream>>>(
      xq, xk, xv, Wqt, Wkt, Wvt, bq, bk, bv, qb, kbuf, vTb, qscale);

  // attention (batch-major grid: XCD = batch -> K/V L2-resident per XCD)
  attn_kernel<<<dim3(BB, NH, SEQ / 128), 512, 0, stream>>>(qb, kbuf, vTb, ctx);

  // output projection (single-barrier 4-buffer pipeline, fp32 out + bias)
  gemm_out<<<dim3(M / 128, DIM / 128), 256, 0, stream>>>(ctx, Wot, bo, out);
}